// Round 2
// baseline (50115.170 us; speedup 1.0000x reference)
//
#include <hip/hip_runtime.h>

#define NN 50000
#define FF 16
#define TH 10
#define EE 800000

#define TWO_LOG2E 2.8853900817779268f  // 2*log2(e)

__device__ __forceinline__ float fexp2(float x) { return __builtin_amdgcn_exp2f(x); }
__device__ __forceinline__ float frcp(float x) { return __builtin_amdgcn_rcpf(x); }
// tanh(x) = 1 - 2/(exp2(x*2log2e)+1)
__device__ __forceinline__ float ftanh(float x) {
  float e = fexp2(x * TWO_LOG2E);
  return 1.0f - 2.0f * frcp(e + 1.0f);
}

// ---------------- preprocessing ----------------

__global__ void count_kernel(const int* __restrict__ ei, int* __restrict__ counts) {
  int e = blockIdx.x * 256 + threadIdx.x;
  if (e < EE) atomicAdd(&counts[ei[EE + e]], 1);
}

__global__ void scan_kernel(const int* __restrict__ counts, int* __restrict__ row_ptr) {
  __shared__ int lds[1024];
  const int CH = (NN + 1023) / 1024;  // 49
  int t = threadIdx.x;
  int beg = t * CH, end = beg + CH;
  if (beg > NN) beg = NN;
  if (end > NN) end = NN;
  int s = 0;
  for (int i = beg; i < end; i++) s += counts[i];
  lds[t] = s;
  __syncthreads();
  for (int off = 1; off < 1024; off <<= 1) {
    int v = (t >= off) ? lds[t - off] : 0;
    __syncthreads();
    lds[t] += v;
    __syncthreads();
  }
  int run = lds[t] - s;  // exclusive prefix
  for (int i = beg; i < end; i++) { row_ptr[i] = run; run += counts[i]; }
  if (t == 1023) row_ptr[NN] = lds[1023];
}

__global__ void fill_kernel(const int* __restrict__ ei, const float* __restrict__ ea,
                            const int* __restrict__ row_ptr, int* __restrict__ cursor,
                            int* __restrict__ src_sorted, float* __restrict__ ea_sorted) {
  int e = blockIdx.x * 256 + threadIdx.x;
  if (e >= EE) return;
  int d = ei[EE + e];
  int pos = row_ptr[d] + atomicAdd(&cursor[d], 1);
  src_sorted[pos] = ei[e];
  ((float4*)ea_sorted)[pos] = ((const float4*)ea)[e];
}

__global__ void times_kernel(const float* __restrict__ t, float* __restrict__ dts,
                             float* __restrict__ tis) {
  int u = threadIdx.x;
  if (u >= 40) return;
  int iv = u >> 2, fr = u & 3;
  float dti = (t[iv + 1] - t[iv]) * 0.25f;
  dts[u] = dti;
  float t0 = t[iv] + (float)fr * dti;
  const float C[6] = {0.0f, 0.2f, 0.3f, 0.8f, (float)(8.0 / 9.0), 1.0f};
  for (int s = 0; s < 6; s++) tis[u * 6 + s] = t0 + C[s] * dti;
}

// aug_pre[n][j] = b1n[j] + sum_i aug[n][i] * W1n[32+i][j]   (176-dim aug)
__global__ __launch_bounds__(256) void augpre_kernel(
    const float* __restrict__ xh, const float* __restrict__ xm,
    const float* __restrict__ W1n, const float* __restrict__ b1n,
    float* __restrict__ aug_pre) {
  __shared__ float Wl[176 * 64];
  __shared__ float augl[4][176];
  for (int i = threadIdx.x; i < 176 * 64; i += 256) Wl[i] = W1n[32 * 64 + i];
  __syncthreads();
  int wv = threadIdx.x >> 6, j = threadIdx.x & 63;
  float bj = b1n[j];
  for (int base = blockIdx.x * 4; base < NN; base += gridDim.x * 4) {
    int n = base + wv;  // NN % 4 == 0, always valid
    if (j < 16) {
      int f = j;
      float xv[TH], mv[TH], summ = 0.f;
      #pragma unroll
      for (int tt = 0; tt < TH; tt++) {
        xv[tt] = xh[(tt * NN + n) * FF + f];
        mv[tt] = xm[tt * NN + n];
        summ += mv[tt];
      }
      float cnt = fmaxf(summ, 1.0f);
      float mean = 0.f;
      #pragma unroll
      for (int tt = 0; tt < TH; tt++) mean += xv[tt] * mv[tt];
      mean *= frcp(cnt);
      float var = 0.f;
      #pragma unroll
      for (int tt = 0; tt < TH; tt++) { float d = xv[tt] - mean; var += d * d * mv[tt]; }
      var *= frcp(cnt);
      #pragma unroll
      for (int tt = 0; tt < TH - 1; tt++)
        augl[wv][tt * 16 + f] = (xv[tt + 1] - xv[tt]) * (mv[tt + 1] * mv[tt]);
      augl[wv][144 + f] = mean;
      augl[wv][160 + f] = var;
    }
    __syncthreads();
    float acc = bj;
    #pragma unroll 8
    for (int i = 0; i < 176; i++) acc += augl[wv][i] * Wl[i * 64 + j];
    aug_pre[n * 64 + j] = acc;
    __syncthreads();
  }
}

// ---------------- fused vector field + RK combine ----------------
// one wave per 4 nodes, lane = hidden unit; epilogue computes next RK state.

#define UDOT2(aa, cc, base)                                     \
  hx = fmaf(aa.x, Uc[base + 0], hx); hy = fmaf(cc.x, Uc[base + 0], hy); \
  hx = fmaf(aa.y, Uc[base + 1], hx); hy = fmaf(cc.y, Uc[base + 1], hy); \
  hx = fmaf(aa.z, Uc[base + 2], hx); hy = fmaf(cc.z, Uc[base + 2], hy); \
  hx = fmaf(aa.w, Uc[base + 3], hx); hy = fmaf(cc.w, Uc[base + 3], hy);

#define UDOT1(aa, base)                                         \
  hx = fmaf(aa.x, Uc[base + 0], hx); hx = fmaf(aa.y, Uc[base + 1], hx); \
  hx = fmaf(aa.z, Uc[base + 2], hx); hx = fmaf(aa.w, Uc[base + 3], hx);

__global__ __launch_bounds__(256, 3) void vf_kernel(
    const float* __restrict__ xi, float* __restrict__ kout,
    const float* __restrict__ xb, float* __restrict__ xnext,
    const float* __restrict__ kp0, const float* __restrict__ kp1,
    const float* __restrict__ kp2, const float* __restrict__ kp3,
    float c0, float c1, float c2, float c3, float cown,
    const int* __restrict__ row_ptr, const int* __restrict__ srcs,
    const float* __restrict__ eas, const float* __restrict__ aug_pre,
    const float* __restrict__ dts, const float* __restrict__ tis,
    int u, int tidx,
    const float* __restrict__ W1m, const float* __restrict__ b1m,
    const float* __restrict__ W2m, const float* __restrict__ b2m,
    const float* __restrict__ W1n, const float* __restrict__ W2n,
    const float* __restrict__ b2n,
    float* __restrict__ dout, const int* __restrict__ mask_idx, int m) {
  __shared__ float ldsS[4][64];
  __shared__ float ldsA[4][16];
  int wv = threadIdx.x >> 6, j = threadIdx.x & 63;
  int g = j >> 4, kk = j & 15;
  int n0 = (blockIdx.x * 4 + wv) * 4;  // 4 nodes per wave

  // ---- per-lane weights (loaded once, amortized over 4 nodes) ----
  float Uc[16], Ec[4], Xc[16], Ac[16], W2mT[16], W2nT[16];
  #pragma unroll
  for (int i = 0; i < 16; i++) {
    Uc[i] = W1m[i * 64 + j] * TWO_LOG2E;  // prescale: exp2 needs x*2log2e
    Xc[i] = W1n[i * 64 + j];
    Ac[i] = W1n[(16 + i) * 64 + j];
  }
  #pragma unroll
  for (int i = 0; i < 4; i++) Ec[i] = W1m[(32 + i) * 64 + j] * TWO_LOG2E;
  #pragma unroll
  for (int q = 0; q < 16; q++) {
    W2mT[q] = W2m[(g * 16 + q) * 16 + kk];
    W2nT[q] = W2n[(g * 16 + q) * 16 + kk];
  }
  float tw = W1n[208 * 64 + j];
  float b2mk = b2m[kk];
  float b2nk = b2n[kk];
  float ti = tis[tidx];
  float dt = dts[u];

  // ---- Q[dst] for the 4 nodes (V columns live only here) ----
  float q[4];
  {
    float b1 = b1m[j];
    float Vc[16];
    #pragma unroll
    for (int i = 0; i < 16; i++) Vc[i] = W1m[(16 + i) * 64 + j];
    #pragma unroll
    for (int nn = 0; nn < 4; nn++) {
      const float4* xr = (const float4*)(xi + (size_t)(n0 + nn) * 16);
      float4 d0 = xr[0], d1 = xr[1], d2 = xr[2], d3 = xr[3];
      float qq = b1;
      qq += d0.x * Vc[0] + d0.y * Vc[1] + d0.z * Vc[2] + d0.w * Vc[3];
      qq += d1.x * Vc[4] + d1.y * Vc[5] + d1.z * Vc[6] + d1.w * Vc[7];
      qq += d2.x * Vc[8] + d2.y * Vc[9] + d2.z * Vc[10] + d2.w * Vc[11];
      qq += d3.x * Vc[12] + d3.y * Vc[13] + d3.z * Vc[14] + d3.w * Vc[15];
      q[nn] = qq * TWO_LOG2E;
    }
  }

  for (int nn = 0; nn < 4; nn++) {
    int n = n0 + nn;
    int e0s = __builtin_amdgcn_readfirstlane(row_ptr[n]);
    int e1s = __builtin_amdgcn_readfirstlane(row_ptr[n + 1]);
    float Qj = q[nn];
    float sj = 0.f;

    for (int e = e0s; e < e1s;) {
      int cnt = e1s - e;
      if (cnt > 64) cnt = 64;
      int myidx = (j < cnt) ? srcs[e + j] : 0;  // one coalesced load per <=64 edges
      int p = 0;
      for (; p + 1 < cnt; p += 2) {
        int s0 = __builtin_amdgcn_readlane(myidx, p);
        int s1 = __builtin_amdgcn_readlane(myidx, p + 1);
        const float4* r0 = (const float4*)(xi + (size_t)s0 * 16);
        const float4* r1 = (const float4*)(xi + (size_t)s1 * 16);
        float4 a0 = r0[0], a1 = r0[1], a2 = r0[2], a3 = r0[3];
        float4 c0v = r1[0], c1v = r1[1], c2v = r1[2], c3v = r1[3];
        float4 ea0 = ((const float4*)eas)[e + p];
        float4 ea1 = ((const float4*)eas)[e + p + 1];
        float hx = Qj, hy = Qj;
        UDOT2(a0, c0v, 0)
        UDOT2(a1, c1v, 4)
        UDOT2(a2, c2v, 8)
        UDOT2(a3, c3v, 12)
        hx = fmaf(ea0.x, Ec[0], hx); hy = fmaf(ea1.x, Ec[0], hy);
        hx = fmaf(ea0.y, Ec[1], hx); hy = fmaf(ea1.y, Ec[1], hy);
        hx = fmaf(ea0.z, Ec[2], hx); hy = fmaf(ea1.z, Ec[2], hy);
        hx = fmaf(ea0.w, Ec[3], hx); hy = fmaf(ea1.w, Ec[3], hy);
        float E0 = fexp2(hx), E1 = fexp2(hy);
        float t0 = 1.0f - 2.0f * frcp(E0 + 1.0f);
        float t1 = 1.0f - 2.0f * frcp(E1 + 1.0f);
        sj += t0 + t1;
      }
      if (p < cnt) {
        int s0 = __builtin_amdgcn_readlane(myidx, p);
        const float4* r0 = (const float4*)(xi + (size_t)s0 * 16);
        float4 a0 = r0[0], a1 = r0[1], a2 = r0[2], a3 = r0[3];
        float4 ea0 = ((const float4*)eas)[e + p];
        float hx = Qj;
        UDOT1(a0, 0)
        UDOT1(a1, 4)
        UDOT1(a2, 8)
        UDOT1(a3, 12)
        hx = fmaf(ea0.x, Ec[0], hx);
        hx = fmaf(ea0.y, Ec[1], hx);
        hx = fmaf(ea0.z, Ec[2], hx);
        hx = fmaf(ea0.w, Ec[3], hx);
        float E0 = fexp2(hx);
        sj += 1.0f - 2.0f * frcp(E0 + 1.0f);
      }
      e += cnt;
    }

    // agg[k] = sum_j tanh_sum_j * W2m[j][k] + cnt*b2m[k]
    ldsS[wv][j] = sj;
    float pk = 0.f;
    #pragma unroll
    for (int qq = 0; qq < 16; qq++) pk += ldsS[wv][g * 16 + qq] * W2mT[qq];
    pk += __shfl_xor(pk, 16, 64);
    pk += __shfl_xor(pk, 32, 64);
    ldsA[wv][kk] = pk + (float)(e1s - e0s) * b2mk;

    // node MLP
    const float4* xr = (const float4*)(xi + (size_t)n * 16);
    float4 d0 = xr[0], d1 = xr[1], d2 = xr[2], d3 = xr[3];
    float g2 = aug_pre[(size_t)n * 64 + j] + ti * tw;
    g2 += d0.x * Xc[0] + d0.y * Xc[1] + d0.z * Xc[2] + d0.w * Xc[3];
    g2 += d1.x * Xc[4] + d1.y * Xc[5] + d1.z * Xc[6] + d1.w * Xc[7];
    g2 += d2.x * Xc[8] + d2.y * Xc[9] + d2.z * Xc[10] + d2.w * Xc[11];
    g2 += d3.x * Xc[12] + d3.y * Xc[13] + d3.z * Xc[14] + d3.w * Xc[15];
    #pragma unroll
    for (int i = 0; i < 16; i++) g2 += ldsA[wv][i] * Ac[i];
    float h2 = ftanh(g2);

    ldsS[wv][j] = h2;
    float ok = 0.f;
    #pragma unroll
    for (int qq = 0; qq < 16; qq++) ok += ldsS[wv][g * 16 + qq] * W2nT[qq];
    ok += __shfl_xor(ok, 16, 64);
    ok += __shfl_xor(ok, 32, 64);

    // epilogue: write k, fused RK combine, optional output scatter
    if (j < 16) {
      float kown = ok + b2nk;
      int base = n * 16 + j;
      kout[base] = kown;
      float v = xb[base] + dt * cown * kown;
      if (kp0) v = fmaf(dt * c0, kp0[base], v);
      if (kp1) v = fmaf(dt * c1, kp1[base], v);
      if (kp2) v = fmaf(dt * c2, kp2[base], v);
      if (kp3) v = fmaf(dt * c3, kp3[base], v);
      xnext[base] = v;
      if (m >= 0) {
        #pragma unroll
        for (int rr = 0; rr < 10; rr++)
          if (mask_idx[rr] == m) dout[rr * (NN * 16) + base] = v;
      }
    }
  }
}

// ---------------- host ----------------

extern "C" void kernel_launch(void* const* d_in, const int* in_sizes, int n_in,
                              void* d_out, int out_size, void* d_ws, size_t ws_size,
                              hipStream_t stream) {
  const float* x_hist = (const float*)d_in[0];
  const float* x_mask = (const float*)d_in[1];
  const int* edge_index = (const int*)d_in[2];
  const float* edge_attr = (const float*)d_in[3];
  const float* t = (const float*)d_in[4];
  const int* mask_idx = (const int*)d_in[5];
  const float* W1m = (const float*)d_in[6];
  const float* b1m = (const float*)d_in[7];
  const float* W2m = (const float*)d_in[8];
  const float* b2m = (const float*)d_in[9];
  const float* W1n = (const float*)d_in[10];
  const float* b1n = (const float*)d_in[11];
  const float* W2n = (const float*)d_in[12];
  const float* b2n = (const float*)d_in[13];
  float* out = (float*)d_out;

  size_t off = 0;
  char* wsb = (char*)d_ws;
  auto alloc = [&](size_t bytes) -> void* {
    void* p = (void*)(wsb + off);
    off += (bytes + 255) & ~(size_t)255;
    return p;
  };
  int* row_ptr = (int*)alloc((NN + 1) * sizeof(int));
  int* counts = (int*)alloc(NN * sizeof(int));
  int* src_sorted = (int*)alloc(EE * sizeof(int));
  float* ea_sorted = (float*)alloc((size_t)EE * 4 * sizeof(float));
  float* aug_pre = (float*)alloc((size_t)NN * 64 * sizeof(float));
  float* xA = (float*)alloc((size_t)NN * FF * sizeof(float));
  float* xB = (float*)alloc((size_t)NN * FF * sizeof(float));
  float* xiA = (float*)alloc((size_t)NN * FF * sizeof(float));
  float* xiB = (float*)alloc((size_t)NN * FF * sizeof(float));
  float* kb[6];
  for (int i = 0; i < 6; i++) kb[i] = (float*)alloc((size_t)NN * FF * sizeof(float));
  float* dts = (float*)alloc(40 * sizeof(float));
  float* tis = (float*)alloc(240 * sizeof(float));

  // CSR build
  hipMemsetAsync(counts, 0, NN * sizeof(int), stream);
  count_kernel<<<(EE + 255) / 256, 256, 0, stream>>>(edge_index, counts);
  scan_kernel<<<1, 1024, 0, stream>>>(counts, row_ptr);
  hipMemsetAsync(counts, 0, NN * sizeof(int), stream);
  fill_kernel<<<(EE + 255) / 256, 256, 0, stream>>>(edge_index, edge_attr, row_ptr, counts,
                                                    src_sorted, ea_sorted);
  augpre_kernel<<<256, 256, 0, stream>>>(x_hist, x_mask, W1n, b1n, aug_pre);
  times_kernel<<<1, 64, 0, stream>>>(t, dts, tis);
  hipMemcpyAsync(xA, x_hist + (size_t)9 * NN * FF, (size_t)NN * FF * sizeof(float),
                 hipMemcpyDeviceToDevice, stream);

  const int VG = NN / 16;  // 3125 blocks: 4 waves * 4 nodes
  float* x = xA;
  float* xn = xB;

  auto vf = [&](const float* xin, float* ko, float* xnext,
                const float* p0, const float* p1, const float* p2, const float* p3,
                float c0, float c1, float c2, float c3, float cown,
                int u, int stage, float* doutp, int m) {
    vf_kernel<<<VG, 256, 0, stream>>>(xin, ko, x, xnext, p0, p1, p2, p3,
                                      c0, c1, c2, c3, cown,
                                      row_ptr, src_sorted, ea_sorted, aug_pre,
                                      dts, tis, u, u * 6 + stage,
                                      W1m, b1m, W2m, b2m, W1n, W2n, b2n,
                                      doutp, mask_idx, m);
  };

  for (int u = 0; u < 40; ++u) {
    vf(x, kb[0], xiA, nullptr, nullptr, nullptr, nullptr,
       0.f, 0.f, 0.f, 0.f, 0.2f, u, 0, nullptr, -1);
    vf(xiA, kb[1], xiB, kb[0], nullptr, nullptr, nullptr,
       0.075f, 0.f, 0.f, 0.f, 0.225f, u, 1, nullptr, -1);
    vf(xiB, kb[2], xiA, kb[0], kb[1], nullptr, nullptr,
       (float)(44.0 / 45.0), (float)(-56.0 / 15.0), 0.f, 0.f, (float)(32.0 / 9.0),
       u, 2, nullptr, -1);
    vf(xiA, kb[3], xiB, kb[0], kb[1], kb[2], nullptr,
       (float)(19372.0 / 6561.0), (float)(-25360.0 / 2187.0), (float)(64448.0 / 6561.0),
       0.f, (float)(-212.0 / 729.0), u, 3, nullptr, -1);
    vf(xiB, kb[4], xiA, kb[0], kb[1], kb[2], kb[3],
       (float)(9017.0 / 3168.0), (float)(-355.0 / 33.0), (float)(46732.0 / 5247.0),
       (float)(49.0 / 176.0), (float)(-5103.0 / 18656.0), u, 4, nullptr, -1);
    int m = ((u & 3) == 3) ? (u >> 2) : -1;
    vf(xiA, kb[5], xn, kb[0], kb[2], kb[3], kb[4],
       (float)(35.0 / 384.0), (float)(500.0 / 1113.0), (float)(125.0 / 192.0),
       (float)(-2187.0 / 6784.0), (float)(11.0 / 84.0), u, 5, out, m);
    float* tmp = x; x = xn; xn = tmp;
  }
}

// Round 3
// 21104.016 us; speedup vs baseline: 2.3747x; 2.3747x over previous
//
#include <hip/hip_runtime.h>

#define NN 50000
#define FF 16
#define TH 10
#define EE 800000

#define TWO_LOG2E 2.8853900817779268f  // 2*log2(e)

__device__ __forceinline__ float fexp2(float x) { return __builtin_amdgcn_exp2f(x); }
__device__ __forceinline__ float frcp(float x) { return __builtin_amdgcn_rcpf(x); }
// tanh(x) = 1 - 2/(exp2(x*2log2e)+1); operand pre-scaled by TWO_LOG2E below.
__device__ __forceinline__ float ftanh_pre(float xs) {
  float e = fexp2(xs);
  return 1.0f - 2.0f * frcp(e + 1.0f);
}

// ---------------- preprocessing ----------------

__global__ void count_kernel(const int* __restrict__ ei, int* __restrict__ counts) {
  int e = blockIdx.x * 256 + threadIdx.x;
  if (e < EE) atomicAdd(&counts[ei[EE + e]], 1);
}

__global__ void scan_kernel(const int* __restrict__ counts, int* __restrict__ row_ptr) {
  __shared__ int lds[1024];
  const int CH = (NN + 1023) / 1024;  // 49
  int t = threadIdx.x;
  int beg = t * CH, end = beg + CH;
  if (beg > NN) beg = NN;
  if (end > NN) end = NN;
  int s = 0;
  for (int i = beg; i < end; i++) s += counts[i];
  lds[t] = s;
  __syncthreads();
  for (int off = 1; off < 1024; off <<= 1) {
    int v = (t >= off) ? lds[t - off] : 0;
    __syncthreads();
    lds[t] += v;
    __syncthreads();
  }
  int run = lds[t] - s;  // exclusive prefix
  for (int i = beg; i < end; i++) { row_ptr[i] = run; run += counts[i]; }
  if (t == 1023) row_ptr[NN] = lds[1023];
}

__global__ void fill_kernel(const int* __restrict__ ei, const float* __restrict__ ea,
                            const int* __restrict__ row_ptr, int* __restrict__ cursor,
                            int* __restrict__ src_sorted, float* __restrict__ ea_sorted) {
  int e = blockIdx.x * 256 + threadIdx.x;
  if (e >= EE) return;
  int d = ei[EE + e];
  int pos = row_ptr[d] + atomicAdd(&cursor[d], 1);
  src_sorted[pos] = ei[e];
  ((float4*)ea_sorted)[pos] = ((const float4*)ea)[e];
}

__global__ void times_kernel(const float* __restrict__ t, float* __restrict__ dts,
                             float* __restrict__ tis) {
  int u = threadIdx.x;
  if (u >= 40) return;
  int iv = u >> 2, fr = u & 3;
  float dti = (t[iv + 1] - t[iv]) * 0.25f;
  dts[u] = dti;
  float t0 = t[iv] + (float)fr * dti;
  const float C[6] = {0.0f, 0.2f, 0.3f, 0.8f, (float)(8.0 / 9.0), 1.0f};
  for (int s = 0; s < 6; s++) tis[u * 6 + s] = t0 + C[s] * dti;
}

// aug_pre[n][j] = b1n[j] + sum_i aug[n][i] * W1n[32+i][j]   (176-dim aug)
__global__ __launch_bounds__(256) void augpre_kernel(
    const float* __restrict__ xh, const float* __restrict__ xm,
    const float* __restrict__ W1n, const float* __restrict__ b1n,
    float* __restrict__ aug_pre) {
  __shared__ float Wl[176 * 64];
  __shared__ float augl[4][176];
  for (int i = threadIdx.x; i < 176 * 64; i += 256) Wl[i] = W1n[32 * 64 + i];
  __syncthreads();
  int wv = threadIdx.x >> 6, j = threadIdx.x & 63;
  float bj = b1n[j];
  for (int base = blockIdx.x * 4; base < NN; base += gridDim.x * 4) {
    int n = base + wv;  // NN % 4 == 0, always valid
    if (j < 16) {
      int f = j;
      float xv[TH], mv[TH], summ = 0.f;
      #pragma unroll
      for (int tt = 0; tt < TH; tt++) {
        xv[tt] = xh[(tt * NN + n) * FF + f];
        mv[tt] = xm[tt * NN + n];
        summ += mv[tt];
      }
      float cnt = fmaxf(summ, 1.0f);
      float mean = 0.f;
      #pragma unroll
      for (int tt = 0; tt < TH; tt++) mean += xv[tt] * mv[tt];
      mean *= frcp(cnt);
      float var = 0.f;
      #pragma unroll
      for (int tt = 0; tt < TH; tt++) { float d = xv[tt] - mean; var += d * d * mv[tt]; }
      var *= frcp(cnt);
      #pragma unroll
      for (int tt = 0; tt < TH - 1; tt++)
        augl[wv][tt * 16 + f] = (xv[tt + 1] - xv[tt]) * (mv[tt + 1] * mv[tt]);
      augl[wv][144 + f] = mean;
      augl[wv][160 + f] = var;
    }
    __syncthreads();
    float acc = bj;
    #pragma unroll 8
    for (int i = 0; i < 176; i++) acc += augl[wv][i] * Wl[i * 64 + j];
    aug_pre[n * 64 + j] = acc;
    __syncthreads();
  }
}

// ---------------- fused vector field + RK combine ----------------
// 1 node per wave (50K waves: many short chains for latency hiding).
// lane = hidden unit j. Edge indices preloaded 64-at-a-time coalesced,
// distributed to the scalar chain via v_readlane (no per-edge index load).

#define EDOT(R0, R1, R2, R3, EA, H)                          \
  H = fmaf(R0.x, Uc[0], H);  H = fmaf(R0.y, Uc[1], H);       \
  H = fmaf(R0.z, Uc[2], H);  H = fmaf(R0.w, Uc[3], H);       \
  H = fmaf(R1.x, Uc[4], H);  H = fmaf(R1.y, Uc[5], H);       \
  H = fmaf(R1.z, Uc[6], H);  H = fmaf(R1.w, Uc[7], H);       \
  H = fmaf(R2.x, Uc[8], H);  H = fmaf(R2.y, Uc[9], H);       \
  H = fmaf(R2.z, Uc[10], H); H = fmaf(R2.w, Uc[11], H);      \
  H = fmaf(R3.x, Uc[12], H); H = fmaf(R3.y, Uc[13], H);      \
  H = fmaf(R3.z, Uc[14], H); H = fmaf(R3.w, Uc[15], H);      \
  H = fmaf(EA.x, Ec[0], H);  H = fmaf(EA.y, Ec[1], H);       \
  H = fmaf(EA.z, Ec[2], H);  H = fmaf(EA.w, Ec[3], H);

__global__ __launch_bounds__(256, 3) void vf_kernel(
    const float* __restrict__ xi, float* __restrict__ kout,
    const float* __restrict__ xb, float* __restrict__ xnext,
    const float* __restrict__ kp0, const float* __restrict__ kp1,
    const float* __restrict__ kp2, const float* __restrict__ kp3,
    float c0, float c1, float c2, float c3, float cown,
    const int* __restrict__ row_ptr, const int* __restrict__ srcs,
    const float* __restrict__ eas, const float* __restrict__ aug_pre,
    const float* __restrict__ dts, const float* __restrict__ tis,
    int u, int tidx,
    const float* __restrict__ W1m, const float* __restrict__ b1m,
    const float* __restrict__ W2m, const float* __restrict__ b2m,
    const float* __restrict__ W1n, const float* __restrict__ W2n,
    const float* __restrict__ b2n,
    float* __restrict__ dout, const int* __restrict__ mask_idx, int m) {
  __shared__ float ldsS[4][64];
  __shared__ float ldsA[4][16];
  int wv = threadIdx.x >> 6, j = threadIdx.x & 63;
  int g = j >> 4, kk = j & 15;
  int n = blockIdx.x * 4 + wv;
  int n_s = __builtin_amdgcn_readfirstlane(n);

  // edge-MLP weight columns (prescaled so tanh needs bare exp2)
  float Uc[16], Ec[4];
  #pragma unroll
  for (int i = 0; i < 16; i++) Uc[i] = W1m[i * 64 + j] * TWO_LOG2E;
  #pragma unroll
  for (int i = 0; i < 4; i++) Ec[i] = W1m[(32 + i) * 64 + j] * TWO_LOG2E;

  // Qj = (b1m + x[dst]·V) prescaled
  float Qj;
  {
    const float4* xr = (const float4*)(xi + (size_t)n_s * 16);
    float4 d0 = xr[0], d1 = xr[1], d2 = xr[2], d3 = xr[3];
    float qq = b1m[j];
    #pragma unroll
    for (int i = 0; i < 4; i++) {
      float vc0 = W1m[(16 + 4 * i + 0) * 64 + j];
      float vc1 = W1m[(16 + 4 * i + 1) * 64 + j];
      float vc2 = W1m[(16 + 4 * i + 2) * 64 + j];
      float vc3 = W1m[(16 + 4 * i + 3) * 64 + j];
      float4 dd = (i == 0) ? d0 : (i == 1) ? d1 : (i == 2) ? d2 : d3;
      qq += dd.x * vc0 + dd.y * vc1 + dd.z * vc2 + dd.w * vc3;
    }
    Qj = qq * TWO_LOG2E;
  }

  int e0s = __builtin_amdgcn_readfirstlane(row_ptr[n_s]);
  int e1s = __builtin_amdgcn_readfirstlane(row_ptr[n_s + 1]);
  float sj = 0.f;

  for (int e = e0s; e < e1s; e += 64) {
    int cnt = e1s - e;
    if (cnt > 64) cnt = 64;
    int myidx = (j < cnt) ? srcs[e + j] : 0;  // one coalesced load per <=64 edges
    int p = 0;
    // 4-wide: 16 row loads + 4 ea loads in flight per iteration
    for (; p + 3 < cnt; p += 4) {
      int s0 = __builtin_amdgcn_readlane(myidx, p);
      int s1 = __builtin_amdgcn_readlane(myidx, p + 1);
      int s2 = __builtin_amdgcn_readlane(myidx, p + 2);
      int s3 = __builtin_amdgcn_readlane(myidx, p + 3);
      const float4* r0 = (const float4*)(xi + (size_t)s0 * 16);
      const float4* r1 = (const float4*)(xi + (size_t)s1 * 16);
      const float4* r2 = (const float4*)(xi + (size_t)s2 * 16);
      const float4* r3 = (const float4*)(xi + (size_t)s3 * 16);
      float4 A0 = r0[0], A1 = r0[1], A2 = r0[2], A3 = r0[3];
      float4 B0 = r1[0], B1 = r1[1], B2 = r1[2], B3 = r1[3];
      float4 C0 = r2[0], C1 = r2[1], C2 = r2[2], C3 = r2[3];
      float4 D0 = r3[0], D1 = r3[1], D2 = r3[2], D3 = r3[3];
      float4 ea0 = ((const float4*)eas)[e + p];
      float4 ea1 = ((const float4*)eas)[e + p + 1];
      float4 ea2 = ((const float4*)eas)[e + p + 2];
      float4 ea3 = ((const float4*)eas)[e + p + 3];
      float h0 = Qj, h1 = Qj, h2 = Qj, h3 = Qj;
      EDOT(A0, A1, A2, A3, ea0, h0)
      EDOT(B0, B1, B2, B3, ea1, h1)
      EDOT(C0, C1, C2, C3, ea2, h2)
      EDOT(D0, D1, D2, D3, ea3, h3)
      sj += ftanh_pre(h0) + ftanh_pre(h1);
      sj += ftanh_pre(h2) + ftanh_pre(h3);
    }
    for (; p < cnt; p++) {
      int s0 = __builtin_amdgcn_readlane(myidx, p);
      const float4* r0 = (const float4*)(xi + (size_t)s0 * 16);
      float4 A0 = r0[0], A1 = r0[1], A2 = r0[2], A3 = r0[3];
      float4 ea0 = ((const float4*)eas)[e + p];
      float h0 = Qj;
      EDOT(A0, A1, A2, A3, ea0, h0)
      sj += ftanh_pre(h0);
    }
  }

  // agg[k] = sum_j tanh_sum_j * W2m[j][k] + deg*b2m[k]  (4-group LDS transpose)
  float W2mT[16];
  #pragma unroll
  for (int q = 0; q < 16; q++) W2mT[q] = W2m[(g * 16 + q) * 16 + kk];
  ldsS[wv][j] = sj;
  float pk = 0.f;
  #pragma unroll
  for (int q = 0; q < 16; q++) pk += ldsS[wv][g * 16 + q] * W2mT[q];
  pk += __shfl_xor(pk, 16, 64);
  pk += __shfl_xor(pk, 32, 64);
  ldsA[wv][kk] = pk + (float)(e1s - e0s) * b2m[kk];

  // node MLP
  float Xc[16], Ac[16];
  #pragma unroll
  for (int i = 0; i < 16; i++) { Xc[i] = W1n[i * 64 + j]; Ac[i] = W1n[(16 + i) * 64 + j]; }
  float tw = W1n[208 * 64 + j];
  float ti = tis[tidx];
  const float4* xr = (const float4*)(xi + (size_t)n_s * 16);
  float4 d0 = xr[0], d1 = xr[1], d2 = xr[2], d3 = xr[3];
  float g2 = aug_pre[(size_t)n * 64 + j] + ti * tw;
  g2 += d0.x * Xc[0] + d0.y * Xc[1] + d0.z * Xc[2] + d0.w * Xc[3];
  g2 += d1.x * Xc[4] + d1.y * Xc[5] + d1.z * Xc[6] + d1.w * Xc[7];
  g2 += d2.x * Xc[8] + d2.y * Xc[9] + d2.z * Xc[10] + d2.w * Xc[11];
  g2 += d3.x * Xc[12] + d3.y * Xc[13] + d3.z * Xc[14] + d3.w * Xc[15];
  #pragma unroll
  for (int i = 0; i < 16; i++) g2 += ldsA[wv][i] * Ac[i];
  float h2 = ftanh_pre(g2 * TWO_LOG2E);

  float W2nT[16];
  #pragma unroll
  for (int q = 0; q < 16; q++) W2nT[q] = W2n[(g * 16 + q) * 16 + kk];
  ldsS[wv][j] = h2;
  float ok = 0.f;
  #pragma unroll
  for (int q = 0; q < 16; q++) ok += ldsS[wv][g * 16 + q] * W2nT[q];
  ok += __shfl_xor(ok, 16, 64);
  ok += __shfl_xor(ok, 32, 64);

  // epilogue: write k, fused RK combine, optional output scatter
  if (j < 16) {
    float dt = dts[u];
    float kown = ok + b2n[j];
    int base = n * 16 + j;
    kout[base] = kown;
    float v = xb[base] + dt * cown * kown;
    if (kp0) v = fmaf(dt * c0, kp0[base], v);
    if (kp1) v = fmaf(dt * c1, kp1[base], v);
    if (kp2) v = fmaf(dt * c2, kp2[base], v);
    if (kp3) v = fmaf(dt * c3, kp3[base], v);
    xnext[base] = v;
    if (m >= 0) {
      #pragma unroll
      for (int rr = 0; rr < 10; rr++)
        if (mask_idx[rr] == m) dout[rr * (NN * 16) + base] = v;
    }
  }
}

// ---------------- host ----------------

extern "C" void kernel_launch(void* const* d_in, const int* in_sizes, int n_in,
                              void* d_out, int out_size, void* d_ws, size_t ws_size,
                              hipStream_t stream) {
  const float* x_hist = (const float*)d_in[0];
  const float* x_mask = (const float*)d_in[1];
  const int* edge_index = (const int*)d_in[2];
  const float* edge_attr = (const float*)d_in[3];
  const float* t = (const float*)d_in[4];
  const int* mask_idx = (const int*)d_in[5];
  const float* W1m = (const float*)d_in[6];
  const float* b1m = (const float*)d_in[7];
  const float* W2m = (const float*)d_in[8];
  const float* b2m = (const float*)d_in[9];
  const float* W1n = (const float*)d_in[10];
  const float* b1n = (const float*)d_in[11];
  const float* W2n = (const float*)d_in[12];
  const float* b2n = (const float*)d_in[13];
  float* out = (float*)d_out;

  size_t off = 0;
  char* wsb = (char*)d_ws;
  auto alloc = [&](size_t bytes) -> void* {
    void* p = (void*)(wsb + off);
    off += (bytes + 255) & ~(size_t)255;
    return p;
  };
  int* row_ptr = (int*)alloc((NN + 1) * sizeof(int));
  int* counts = (int*)alloc(NN * sizeof(int));
  int* src_sorted = (int*)alloc(EE * sizeof(int));
  float* ea_sorted = (float*)alloc((size_t)EE * 4 * sizeof(float));
  float* aug_pre = (float*)alloc((size_t)NN * 64 * sizeof(float));
  float* xA = (float*)alloc((size_t)NN * FF * sizeof(float));
  float* xB = (float*)alloc((size_t)NN * FF * sizeof(float));
  float* xiA = (float*)alloc((size_t)NN * FF * sizeof(float));
  float* xiB = (float*)alloc((size_t)NN * FF * sizeof(float));
  float* kb[6];
  for (int i = 0; i < 6; i++) kb[i] = (float*)alloc((size_t)NN * FF * sizeof(float));
  float* dts = (float*)alloc(40 * sizeof(float));
  float* tis = (float*)alloc(240 * sizeof(float));

  // CSR build
  hipMemsetAsync(counts, 0, NN * sizeof(int), stream);
  count_kernel<<<(EE + 255) / 256, 256, 0, stream>>>(edge_index, counts);
  scan_kernel<<<1, 1024, 0, stream>>>(counts, row_ptr);
  hipMemsetAsync(counts, 0, NN * sizeof(int), stream);
  fill_kernel<<<(EE + 255) / 256, 256, 0, stream>>>(edge_index, edge_attr, row_ptr, counts,
                                                    src_sorted, ea_sorted);
  augpre_kernel<<<256, 256, 0, stream>>>(x_hist, x_mask, W1n, b1n, aug_pre);
  times_kernel<<<1, 64, 0, stream>>>(t, dts, tis);
  hipMemcpyAsync(xA, x_hist + (size_t)9 * NN * FF, (size_t)NN * FF * sizeof(float),
                 hipMemcpyDeviceToDevice, stream);

  const int VG = NN / 4;  // 12500 blocks, 4 waves, 1 node/wave
  float* x = xA;
  float* xn = xB;

  auto vf = [&](const float* xin, float* ko, float* xnext,
                const float* p0, const float* p1, const float* p2, const float* p3,
                float c0, float c1, float c2, float c3, float cown,
                int u, int stage, float* doutp, int m) {
    vf_kernel<<<VG, 256, 0, stream>>>(xin, ko, x, xnext, p0, p1, p2, p3,
                                      c0, c1, c2, c3, cown,
                                      row_ptr, src_sorted, ea_sorted, aug_pre,
                                      dts, tis, u, u * 6 + stage,
                                      W1m, b1m, W2m, b2m, W1n, W2n, b2n,
                                      doutp, mask_idx, m);
  };

  for (int u = 0; u < 40; ++u) {
    vf(x, kb[0], xiA, nullptr, nullptr, nullptr, nullptr,
       0.f, 0.f, 0.f, 0.f, 0.2f, u, 0, nullptr, -1);
    vf(xiA, kb[1], xiB, kb[0], nullptr, nullptr, nullptr,
       0.075f, 0.f, 0.f, 0.f, 0.225f, u, 1, nullptr, -1);
    vf(xiB, kb[2], xiA, kb[0], kb[1], nullptr, nullptr,
       (float)(44.0 / 45.0), (float)(-56.0 / 15.0), 0.f, 0.f, (float)(32.0 / 9.0),
       u, 2, nullptr, -1);
    vf(xiA, kb[3], xiB, kb[0], kb[1], kb[2], nullptr,
       (float)(19372.0 / 6561.0), (float)(-25360.0 / 2187.0), (float)(64448.0 / 6561.0),
       0.f, (float)(-212.0 / 729.0), u, 3, nullptr, -1);
    vf(xiB, kb[4], xiA, kb[0], kb[1], kb[2], kb[3],
       (float)(9017.0 / 3168.0), (float)(-355.0 / 33.0), (float)(46732.0 / 5247.0),
       (float)(49.0 / 176.0), (float)(-5103.0 / 18656.0), u, 4, nullptr, -1);
    int m = ((u & 3) == 3) ? (u >> 2) : -1;
    vf(xiA, kb[5], xn, kb[0], kb[2], kb[3], kb[4],
       (float)(35.0 / 384.0), (float)(500.0 / 1113.0), (float)(125.0 / 192.0),
       (float)(-2187.0 / 6784.0), (float)(11.0 / 84.0), u, 5, out, m);
    float* tmp = x; x = xn; xn = tmp;
  }
}